// Round 1
// baseline (276.280 us; speedup 1.0000x reference)
//
#include <hip/hip_runtime.h>
#include <math.h>

#define RED_BLOCKS 256
#define ORD_NEG_INF 0x007fffffu  // f2ord(-inf)

// Monotone order-preserving float->uint mapping (for integer atomicMax on floats)
__device__ __forceinline__ unsigned f2ord(float f) {
    unsigned u = __float_as_uint(f);
    return (u & 0x80000000u) ? ~u : (u | 0x80000000u);
}
__device__ __forceinline__ float ord2f(unsigned u) {
    unsigned v = (u & 0x80000000u) ? (u & 0x7fffffffu) : ~u;
    return __uint_as_float(v);
}

// One 64-lane wave per row: h[row] = dot(loss[row,:200], W[:200]); also init seg-max arrays.
__global__ void k_h_init(const float* __restrict__ loss, const float* __restrict__ Ws,
                         float* __restrict__ h, unsigned* __restrict__ preOrd,
                         unsigned* __restrict__ sucOrd, int n) {
    int wave = threadIdx.x >> 6, lane = threadIdx.x & 63;
    int row = blockIdx.x * 4 + wave;
    if (row >= n) return;
    float acc = 0.0f;
    if (lane < 50) {  // 200 floats = 50 float4 (row stride 800B, 16B-aligned)
        float4 a = ((const float4*)(loss + (size_t)row * 200))[lane];
        float4 w = ((const float4*)Ws)[lane];
        acc = a.x * w.x + a.y * w.y + a.z * w.z + a.w * w.w;
    }
    #pragma unroll
    for (int off = 32; off > 0; off >>= 1) acc += __shfl_down(acc, off);
    if (lane == 0) {
        h[row] = acc;
        preOrd[row] = ORD_NEG_INF;
        sucOrd[row] = ORD_NEG_INF;
    }
}

// One thread per edge: scatter-max h[src]->pre[dst], h[dst]->suc[src], skipping self-loops.
__global__ void k_edges(const int* __restrict__ src, const int* __restrict__ dst,
                        const float* __restrict__ h, unsigned* __restrict__ preOrd,
                        unsigned* __restrict__ sucOrd, int ne) {
    int e = blockIdx.x * blockDim.x + threadIdx.x;
    if (e >= ne) return;
    int s = src[e], d = dst[e];
    if (s == d) return;
    atomicMax(&preOrd[d], f2ord(h[s]));
    atomicMax(&sucOrd[s], f2ord(h[d]));
}

// logit[i] = h[i] + w0*pre + w1*suc  (untouched seg-max slots -> 0.0, per DGL fill)
// + fixed-grid block-partial max.
__global__ void k_logit_max(const float* __restrict__ h, const unsigned* __restrict__ preOrd,
                            const unsigned* __restrict__ sucOrd, const float* __restrict__ Wg,
                            float* __restrict__ logit, float* __restrict__ maxPart, int n) {
    __shared__ float sm[256];
    float w0 = Wg[0], w1 = Wg[1];
    float m = -INFINITY;
    for (int i = blockIdx.x * 256 + threadIdx.x; i < n; i += 256 * RED_BLOCKS) {
        unsigned p = preOrd[i], s = sucOrd[i];
        float pf = (p == ORD_NEG_INF) ? 0.0f : ord2f(p);
        float sf = (s == ORD_NEG_INF) ? 0.0f : ord2f(s);
        float l = h[i] + w0 * pf + w1 * sf;
        logit[i] = l;
        m = fmaxf(m, l);
    }
    sm[threadIdx.x] = m;
    __syncthreads();
    for (int off = 128; off > 0; off >>= 1) {
        if (threadIdx.x < off) sm[threadIdx.x] = fmaxf(sm[threadIdx.x], sm[threadIdx.x + off]);
        __syncthreads();
    }
    if (threadIdx.x == 0) maxPart[blockIdx.x] = sm[0];
}

// Every block redundantly (deterministically) reduces the 256 max-partials, then
// writes exp(l - gmax) to out and produces block-partial sums.
__global__ void k_exp_sum(const float* __restrict__ logit, const float* __restrict__ maxPart,
                          float* __restrict__ out, float* __restrict__ sumPart, int n) {
    __shared__ float sm[256];
    sm[threadIdx.x] = maxPart[threadIdx.x];
    __syncthreads();
    for (int off = 128; off > 0; off >>= 1) {
        if (threadIdx.x < off) sm[threadIdx.x] = fmaxf(sm[threadIdx.x], sm[threadIdx.x + off]);
        __syncthreads();
    }
    float gmax = sm[0];
    __syncthreads();
    float acc = 0.0f;
    for (int i = blockIdx.x * 256 + threadIdx.x; i < n; i += 256 * RED_BLOCKS) {
        float e = expf(logit[i] - gmax);
        out[i] = e;
        acc += e;
    }
    sm[threadIdx.x] = acc;
    __syncthreads();
    for (int off = 128; off > 0; off >>= 1) {
        if (threadIdx.x < off) sm[threadIdx.x] += sm[threadIdx.x + off];
        __syncthreads();
    }
    if (threadIdx.x == 0) sumPart[blockIdx.x] = sm[0];
}

// Redundant deterministic sum-reduce of the 256 partials, then scale the output.
__global__ void k_norm(const float* __restrict__ sumPart, float* __restrict__ out, int n) {
    __shared__ float sm[256];
    sm[threadIdx.x] = sumPart[threadIdx.x];
    __syncthreads();
    for (int off = 128; off > 0; off >>= 1) {
        if (threadIdx.x < off) sm[threadIdx.x] += sm[threadIdx.x + off];
        __syncthreads();
    }
    float inv = 1.0f / sm[0];
    for (int i = blockIdx.x * 256 + threadIdx.x; i < n; i += 256 * RED_BLOCKS) out[i] *= inv;
}

extern "C" void kernel_launch(void* const* d_in, const int* in_sizes, int n_in,
                              void* d_out, int out_size, void* d_ws, size_t ws_size,
                              hipStream_t stream) {
    const float* loss = (const float*)d_in[0];   // [N, 200]
    const float* Ws   = (const float*)d_in[1];   // [1, 200]
    const float* Wg   = (const float*)d_in[2];   // [1, 2]
    const int* esrc   = (const int*)d_in[3];     // [E]
    const int* edst   = (const int*)d_in[4];     // [E]
    float* out = (float*)d_out;                  // [N]

    const int n  = in_sizes[0] / 200;
    const int ne = in_sizes[3];

    // Workspace layout (all f32/u32 words): h | preOrd | sucOrd | logit | maxPart | sumPart
    float*    h       = (float*)d_ws;
    unsigned* preOrd  = (unsigned*)(h + n);
    unsigned* sucOrd  = preOrd + n;
    float*    logit   = (float*)(sucOrd + n);
    float*    maxPart = logit + n;
    float*    sumPart = maxPart + RED_BLOCKS;

    k_h_init<<<(n + 3) / 4, 256, 0, stream>>>(loss, Ws, h, preOrd, sucOrd, n);
    k_edges<<<(ne + 255) / 256, 256, 0, stream>>>(esrc, edst, h, preOrd, sucOrd, ne);
    k_logit_max<<<RED_BLOCKS, 256, 0, stream>>>(h, preOrd, sucOrd, Wg, logit, maxPart, n);
    k_exp_sum<<<RED_BLOCKS, 256, 0, stream>>>(logit, maxPart, out, sumPart, n);
    k_norm<<<RED_BLOCKS, 256, 0, stream>>>(sumPart, out, n);
}

// Round 2
// 245.965 us; speedup vs baseline: 1.1233x; 1.1233x over previous
//
#include <hip/hip_runtime.h>
#include <math.h>

#define RED_BLOCKS 256
#define ORD_NEG_INF 0x007fffffu  // f2ord(-inf)

// Monotone order-preserving float->uint mapping (for integer atomicMax on floats)
__device__ __forceinline__ unsigned f2ord(float f) {
    unsigned u = __float_as_uint(f);
    return (u & 0x80000000u) ? ~u : (u | 0x80000000u);
}
__device__ __forceinline__ float ord2f(unsigned u) {
    unsigned v = (u & 0x80000000u) ? (u & 0x7fffffffu) : ~u;
    return __uint_as_float(v);
}

// One 64-lane wave per row: h[row] = dot(loss[row,:200], W[:200]); also init seg-max arrays.
__global__ void k_h_init(const float* __restrict__ loss, const float* __restrict__ Ws,
                         float* __restrict__ h, unsigned* __restrict__ preOrd,
                         unsigned* __restrict__ sucOrd, int n) {
    int wave = threadIdx.x >> 6, lane = threadIdx.x & 63;
    int row = blockIdx.x * 4 + wave;
    if (row >= n) return;
    float acc = 0.0f;
    if (lane < 50) {  // 200 floats = 50 float4 (row stride 800B, 16B-aligned)
        float4 a = ((const float4*)(loss + (size_t)row * 200))[lane];
        float4 w = ((const float4*)Ws)[lane];
        acc = a.x * w.x + a.y * w.y + a.z * w.z + a.w * w.w;
    }
    #pragma unroll
    for (int off = 32; off > 0; off >>= 1) acc += __shfl_down(acc, off);
    if (lane == 0) {
        h[row] = acc;
        preOrd[row] = ORD_NEG_INF;
        sucOrd[row] = ORD_NEG_INF;
    }
}

// One thread per edge, with a read-filter before each atomic.
// Plain loads of preOrd/sucOrd may be stale (L1 / per-XCD L2), but values only
// grow monotonically, so a stale value is a lower bound: skipping when
// stale >= candidate is always safe; a spurious atomic is merely redundant.
__global__ void k_edges(const int* __restrict__ src, const int* __restrict__ dst,
                        const float* __restrict__ h, unsigned* __restrict__ preOrd,
                        unsigned* __restrict__ sucOrd, int ne) {
    int e = blockIdx.x * blockDim.x + threadIdx.x;
    if (e >= ne) return;
    int s = src[e], d = dst[e];
    if (s == d) return;
    unsigned hs = f2ord(h[s]);
    unsigned hd = f2ord(h[d]);
    if (preOrd[d] < hs) atomicMax(&preOrd[d], hs);
    if (sucOrd[s] < hd) atomicMax(&sucOrd[s], hd);
}

// logit[i] = h[i] + w0*pre + w1*suc  (untouched seg-max slots -> 0.0, per DGL fill)
// + fixed-grid block-partial max.
__global__ void k_logit_max(const float* __restrict__ h, const unsigned* __restrict__ preOrd,
                            const unsigned* __restrict__ sucOrd, const float* __restrict__ Wg,
                            float* __restrict__ logit, float* __restrict__ maxPart, int n) {
    __shared__ float sm[256];
    float w0 = Wg[0], w1 = Wg[1];
    float m = -INFINITY;
    for (int i = blockIdx.x * 256 + threadIdx.x; i < n; i += 256 * RED_BLOCKS) {
        unsigned p = preOrd[i], s = sucOrd[i];
        float pf = (p == ORD_NEG_INF) ? 0.0f : ord2f(p);
        float sf = (s == ORD_NEG_INF) ? 0.0f : ord2f(s);
        float l = h[i] + w0 * pf + w1 * sf;
        logit[i] = l;
        m = fmaxf(m, l);
    }
    sm[threadIdx.x] = m;
    __syncthreads();
    for (int off = 128; off > 0; off >>= 1) {
        if (threadIdx.x < off) sm[threadIdx.x] = fmaxf(sm[threadIdx.x], sm[threadIdx.x + off]);
        __syncthreads();
    }
    if (threadIdx.x == 0) maxPart[blockIdx.x] = sm[0];
}

// Every block redundantly (deterministically) reduces the 256 max-partials, then
// writes exp(l - gmax) to out and produces block-partial sums.
__global__ void k_exp_sum(const float* __restrict__ logit, const float* __restrict__ maxPart,
                          float* __restrict__ out, float* __restrict__ sumPart, int n) {
    __shared__ float sm[256];
    sm[threadIdx.x] = maxPart[threadIdx.x];
    __syncthreads();
    for (int off = 128; off > 0; off >>= 1) {
        if (threadIdx.x < off) sm[threadIdx.x] = fmaxf(sm[threadIdx.x], sm[threadIdx.x + off]);
        __syncthreads();
    }
    float gmax = sm[0];
    __syncthreads();
    float acc = 0.0f;
    for (int i = blockIdx.x * 256 + threadIdx.x; i < n; i += 256 * RED_BLOCKS) {
        float e = expf(logit[i] - gmax);
        out[i] = e;
        acc += e;
    }
    sm[threadIdx.x] = acc;
    __syncthreads();
    for (int off = 128; off > 0; off >>= 1) {
        if (threadIdx.x < off) sm[threadIdx.x] += sm[threadIdx.x + off];
        __syncthreads();
    }
    if (threadIdx.x == 0) sumPart[blockIdx.x] = sm[0];
}

// Redundant deterministic sum-reduce of the 256 partials, then scale the output.
__global__ void k_norm(const float* __restrict__ sumPart, float* __restrict__ out, int n) {
    __shared__ float sm[256];
    sm[threadIdx.x] = sumPart[threadIdx.x];
    __syncthreads();
    for (int off = 128; off > 0; off >>= 1) {
        if (threadIdx.x < off) sm[threadIdx.x] += sm[threadIdx.x + off];
        __syncthreads();
    }
    float inv = 1.0f / sm[0];
    for (int i = blockIdx.x * 256 + threadIdx.x; i < n; i += 256 * RED_BLOCKS) out[i] *= inv;
}

extern "C" void kernel_launch(void* const* d_in, const int* in_sizes, int n_in,
                              void* d_out, int out_size, void* d_ws, size_t ws_size,
                              hipStream_t stream) {
    const float* loss = (const float*)d_in[0];   // [N, 200]
    const float* Ws   = (const float*)d_in[1];   // [1, 200]
    const float* Wg   = (const float*)d_in[2];   // [1, 2]
    const int* esrc   = (const int*)d_in[3];     // [E]
    const int* edst   = (const int*)d_in[4];     // [E]
    float* out = (float*)d_out;                  // [N]

    const int n  = in_sizes[0] / 200;
    const int ne = in_sizes[3];

    // Workspace layout (all f32/u32 words): h | preOrd | sucOrd | logit | maxPart | sumPart
    float*    h       = (float*)d_ws;
    unsigned* preOrd  = (unsigned*)(h + n);
    unsigned* sucOrd  = preOrd + n;
    float*    logit   = (float*)(sucOrd + n);
    float*    maxPart = logit + n;
    float*    sumPart = maxPart + RED_BLOCKS;

    k_h_init<<<(n + 3) / 4, 256, 0, stream>>>(loss, Ws, h, preOrd, sucOrd, n);
    k_edges<<<(ne + 255) / 256, 256, 0, stream>>>(esrc, edst, h, preOrd, sucOrd, ne);
    k_logit_max<<<RED_BLOCKS, 256, 0, stream>>>(h, preOrd, sucOrd, Wg, logit, maxPart, n);
    k_exp_sum<<<RED_BLOCKS, 256, 0, stream>>>(logit, maxPart, out, sumPart, n);
    k_norm<<<RED_BLOCKS, 256, 0, stream>>>(sumPart, out, n);
}